// Round 8
// baseline (565.430 us; speedup 1.0000x reference)
//
#include <hip/hip_runtime.h>
#include <math.h>

#define ENH_PAD 160   // 144 padded to multiple of 32 for MFMA K-loop
#define POSD 16

typedef __attribute__((ext_vector_type(8))) __bf16 bf16x8;
typedef __attribute__((ext_vector_type(4))) float f32x4;

__device__ __forceinline__ unsigned short f2bf(float f){
  unsigned int u = __float_as_uint(f);
  u += 0x7FFF + ((u >> 16) & 1);          // round-to-nearest-even
  return (unsigned short)(u >> 16);
}
__device__ __forceinline__ float bf2f(unsigned short u){
  return __uint_as_float(((unsigned int)u) << 16);
}

// ---- fused front: starts + in-degree + zero bnstats/pooled ------------------
__global__ void k_front(const int* __restrict__ batch, int* __restrict__ starts,
                        const int* __restrict__ dst, int* __restrict__ indeg,
                        float* __restrict__ bnstats, float* __restrict__ pooled,
                        int N, int E){
  int i = blockIdx.x * blockDim.x + threadIdx.x;
  if (i < 1024) bnstats[i] = 0.f;
  if (i < 64 * 256) pooled[i] = 0.f;
  if (i < N){
    int bi = batch[i];
    int bp = (i == 0) ? -1 : batch[i - 1];
    for (int b = bp + 1; b <= bi; ++b) starts[b] = i;
    if (i == N - 1){
      for (int b = bi + 1; b <= 64; ++b) starts[b] = N;
    }
  }
  if (i < E) atomicAdd(&indeg[dst[i]], 1);
}

// ---- Wa[k][j] = sum_c W[k][hd(j)*64+c] * a_{src|dst}[hd(j)][c] --------------
// rows 0..143 -> (W1,a1) into Wa1 ; rows 144..399 -> (W2,a2) into Wa2
__global__ __launch_bounds__(256) void k_wa(
    const float* __restrict__ W1, const float* __restrict__ as1, const float* __restrict__ ad1,
    const float* __restrict__ W2, const float* __restrict__ as2, const float* __restrict__ ad2,
    float* __restrict__ Wa1, float* __restrict__ Wa2){
  int wv = blockIdx.x * 4 + (threadIdx.x >> 6);
  int lane = threadIdx.x & 63;
  const float *W, *as, *ad; float* Wa; int k;
  if (wv < 144){ W = W1; as = as1; ad = ad1; Wa = Wa1; k = wv; }
  else if (wv < 400){ W = W2; as = as2; ad = ad2; Wa = Wa2; k = wv - 144; }
  else return;
  float4 w4 = *(const float4*)(W + (size_t)k * 256 + lane * 4);
  int hd = lane >> 4;
  int c4 = (lane & 15) * 4;
  float4 s4 = *(const float4*)(as + hd * 64 + c4);
  float4 d4 = *(const float4*)(ad + hd * 64 + c4);
  float s = w4.x * s4.x + w4.y * s4.y + w4.z * s4.z + w4.w * s4.w;
  float d = w4.x * d4.x + w4.y * d4.y + w4.z * d4.z + w4.w * d4.w;
  s += __shfl_xor(s, 1); s += __shfl_xor(s, 2); s += __shfl_xor(s, 4); s += __shfl_xor(s, 8);
  d += __shfl_xor(d, 1); d += __shfl_xor(d, 2); d += __shfl_xor(d, 4); d += __shfl_xor(d, 8);
  if ((lane & 15) == 0){
    Wa[k * 8 + hd] = s;
    Wa[k * 8 + 4 + hd] = d;
  }
}

// ---- h0 build (bf16, padded) + fused layer-1 alphas (fp32 inputs) -----------
__global__ __launch_bounds__(256) void k_build_h0(
    const float* __restrict__ x, const int* __restrict__ batch,
    const int* __restrict__ starts, const int* __restrict__ gsize,
    const float* __restrict__ invden,
    const float* __restrict__ W_pos, const float* __restrict__ b_pos,
    const float* __restrict__ Wa1,
    unsigned short* __restrict__ h0,
    float* __restrict__ alpS, float* __restrict__ alpD, int N){
  int n = blockIdx.x * 4 + (threadIdx.x >> 6);
  if (n >= N) return;
  int t = threadIdx.x & 63;
  unsigned short* hrow = h0 + (size_t)n * ENH_PAD;
  float part[8];
  #pragma unroll
  for (int j = 0; j < 8; ++j) part[j] = 0.f;
  if (t < 32){
    const float4* xs = (const float4*)(x + (size_t)n * 128);
    float4 v = xs[t];
    ushort4 o; o.x = f2bf(v.x); o.y = f2bf(v.y); o.z = f2bf(v.z); o.w = f2bf(v.w);
    ((ushort4*)hrow)[t] = o;
    const float* wr = Wa1 + (size_t)(4 * t) * 8;
    #pragma unroll
    for (int j = 0; j < 8; ++j)
      part[j] = v.x * wr[j] + v.y * wr[8 + j] + v.z * wr[16 + j] + v.w * wr[24 + j];
  } else if (t < 48){
    int k = t - 32;
    int b = batch[n];
    int i = n - starts[b];
    int g = gsize[b];
    int row = i / g;
    int col = i - row * g;
    float idn = invden[b];
    float pe = (float)row * idn * W_pos[k] + (float)col * idn * W_pos[POSD + k] + b_pos[k];
    hrow[128 + k] = f2bf(pe);
    const float* wr = Wa1 + (size_t)(128 + k) * 8;
    #pragma unroll
    for (int j = 0; j < 8; ++j) part[j] = pe * wr[j];
  } else {
    hrow[144 + (t - 48)] = 0;     // zero pad cols 144..159
  }
  #pragma unroll
  for (int j = 0; j < 8; ++j){
    #pragma unroll
    for (int off = 32; off; off >>= 1) part[j] += __shfl_xor(part[j], off);
  }
  if (t == 0){
    *(float4*)(alpS + n * 4) = make_float4(part[0], part[1], part[2], part[3]);
    *(float4*)(alpD + n * 4) = make_float4(part[4], part[5], part[6], part[7]);
  }
}

// ---- pack both weights: W [K x 256] fp32 -> Wt [256 x Kp] bf16 --------------
__global__ void k_pack_both(const float* __restrict__ W1, const float* __restrict__ W2,
                            unsigned short* __restrict__ W1t, unsigned short* __restrict__ W2t){
  int idx = blockIdx.x * 256 + threadIdx.x;
  const int n1 = 256 * ENH_PAD;
  if (idx < n1){
    int n = idx / ENH_PAD, k = idx - n * ENH_PAD;
    W1t[idx] = f2bf((k < 144) ? W1[(size_t)k * 256 + n] : 0.f);
  } else {
    int j = idx - n1;
    if (j < 256 * 256){
      int n = j >> 8, k = j & 255;
      W2t[j] = f2bf(W2[(size_t)k * 256 + n]);
    }
  }
}

// ---- bf16 MFMA GEMM: C[M x 256](bf16) = A[M x Kp] * Bt[256 x Kp]^T ----------
#define LDST 40   // LDS row stride in bf16 (2-way bank aliasing, free)
__global__ __launch_bounds__(256) void k_mfma_gemm(
    const unsigned short* __restrict__ A, const unsigned short* __restrict__ Bt,
    unsigned short* __restrict__ C, int M, int Kp){
  __shared__ unsigned short As[128 * LDST];
  __shared__ unsigned short Bs[128 * LDST];
  int t = threadIdx.x;
  int lane = t & 63, wave = t >> 6;
  int wm = (wave >> 1) * 64, wn = (wave & 1) * 64;
  int quad = lane >> 4, l16 = lane & 15;
  int row0 = blockIdx.x * 128;
  int n0 = blockIdx.y * 128;

  f32x4 acc[4][4] = {};

  int eA0 = t, eA1 = t + 256;
  for (int kk = 0; kk < Kp; kk += 32){
    #pragma unroll
    for (int rep = 0; rep < 2; ++rep){
      int e = rep ? eA1 : eA0;
      int r = e >> 2, s = e & 3;
      int grow = row0 + r;
      uint4 va = make_uint4(0, 0, 0, 0);
      if (grow < M) va = *(const uint4*)(A + (size_t)grow * Kp + kk + s * 8);
      *(uint4*)&As[r * LDST + s * 8] = va;
      uint4 vb = *(const uint4*)(Bt + (size_t)(n0 + r) * Kp + kk + s * 8);
      *(uint4*)&Bs[r * LDST + s * 8] = vb;
    }
    __syncthreads();
    bf16x8 af[4], bfr[4];
    #pragma unroll
    for (int i = 0; i < 4; ++i)
      af[i] = *(const bf16x8*)&As[(wm + i * 16 + l16) * LDST + quad * 8];
    #pragma unroll
    for (int j = 0; j < 4; ++j)
      bfr[j] = *(const bf16x8*)&Bs[(wn + j * 16 + l16) * LDST + quad * 8];
    #pragma unroll
    for (int i = 0; i < 4; ++i)
      #pragma unroll
      for (int j = 0; j < 4; ++j)
        acc[i][j] = __builtin_amdgcn_mfma_f32_16x16x32_bf16(af[i], bfr[j], acc[i][j], 0, 0, 0);
    __syncthreads();
  }
  #pragma unroll
  for (int i = 0; i < 4; ++i){
    int rbase = row0 + wm + i * 16 + quad * 4;
    #pragma unroll
    for (int j = 0; j < 4; ++j){
      int col = n0 + wn + j * 16 + l16;
      #pragma unroll
      for (int r = 0; r < 4; ++r){
        int row = rbase + r;
        if (row < M) C[(size_t)row * 256 + col] = f2bf(acc[i][j][r]);
      }
    }
  }
}

// ---- parallel scan of indeg -> row_ptr / cursor -----------------------------
__device__ __forceinline__ int block_excl_scan_256(int val, int* lds){
  int t = threadIdx.x;
  int lane = t & 63, w = t >> 6;
  int incl = val;
  #pragma unroll
  for (int off = 1; off < 64; off <<= 1){
    int v = __shfl_up(incl, off);
    if (lane >= off) incl += v;
  }
  if (lane == 63) lds[w] = incl;
  __syncthreads();
  int wofs = 0;
  #pragma unroll
  for (int i = 0; i < 4; ++i) if (i < w) wofs += lds[i];
  return wofs + incl - val;
}

__global__ __launch_bounds__(256) void k_scan1(const int* __restrict__ indeg,
                                               int* __restrict__ bsums, int N){
  int i = blockIdx.x * 256 + threadIdx.x;
  int v = (i < N) ? indeg[i] : 0;
  int s = v;
  #pragma unroll
  for (int off = 32; off; off >>= 1) s += __shfl_xor(s, off);
  __shared__ int wt[4];
  if ((threadIdx.x & 63) == 0) wt[threadIdx.x >> 6] = s;
  __syncthreads();
  if (threadIdx.x == 0) bsums[blockIdx.x] = wt[0] + wt[1] + wt[2] + wt[3];
}

__global__ __launch_bounds__(1024) void k_scan2_meta(const int* __restrict__ bsums,
                                                     int* __restrict__ boffs,
                                                     int* __restrict__ row_ptr,
                                                     const int* __restrict__ starts,
                                                     int* __restrict__ gsize,
                                                     float* __restrict__ invden,
                                                     float* __restrict__ invcnt,
                                                     int NB, int N){
  int t = threadIdx.x;
  if (t < 64){
    int c = starts[t + 1] - starts[t];
    int g = (int)ceilf(sqrtf((float)c));
    gsize[t] = g;
    int dd = g - 1; if (dd < 1) dd = 1;
    invden[t] = 1.0f / (float)dd;
    invcnt[t] = (c > 0) ? 1.0f / (float)c : 0.0f;
  }
  int v = (t < NB) ? bsums[t] : 0;
  int lane = t & 63, w = t >> 6;
  int incl = v;
  #pragma unroll
  for (int off = 1; off < 64; off <<= 1){
    int x = __shfl_up(incl, off);
    if (lane >= off) incl += x;
  }
  __shared__ int wt[16];
  if (lane == 63) wt[w] = incl;
  __syncthreads();
  int wofs = 0;
  for (int i = 0; i < w; ++i) wofs += wt[i];
  if (t < NB) boffs[t] = wofs + incl - v;
  if (t == 1023){
    int tot = 0;
    for (int i = 0; i < 16; ++i) tot += wt[i];
    row_ptr[N] = tot;
  }
}

__global__ __launch_bounds__(256) void k_scan3(const int* __restrict__ indeg,
                                               const int* __restrict__ boffs,
                                               int* __restrict__ row_ptr,
                                               int* __restrict__ cursor, int N){
  __shared__ int lds[4];
  int i = blockIdx.x * 256 + threadIdx.x;
  int v = (i < N) ? indeg[i] : 0;
  int ex = block_excl_scan_256(v, lds) + boffs[blockIdx.x];
  if (i < N){
    row_ptr[i] = ex;
    cursor[i] = ex;
  }
}

__global__ void k_scatter(const int* __restrict__ src, const int* __restrict__ dst,
                          int* cursor, int* __restrict__ csr_src, int E){
  int e = blockIdx.x * blockDim.x + threadIdx.x;
  if (e < E){
    int slot = atomicAdd(&cursor[dst[e]], 1);
    csr_src[slot] = src[e];
  }
}

// ---- GAT aggregation: one wave/node, 4 heads, batched gathers.
//      Full-16 chunks (no per-edge validity tests) + 4-granular tail. --------
__global__ __launch_bounds__(256) void k_aggregate(const unsigned short* __restrict__ hlin,
                                                   const float* __restrict__ alpS,
                                                   const float* __restrict__ alpD,
                                                   const int* __restrict__ row_ptr,
                                                   const int* __restrict__ csr_src,
                                                   const float* __restrict__ bias,
                                                   unsigned short* __restrict__ outb, int N){
  int n = blockIdx.x * 4 + (threadIdx.x >> 6);
  if (n >= N) return;
  int lane = threadIdx.x & 63;
  int hd = lane >> 4;          // channel-domain head
  int hd2 = lane & 3;          // score-domain head
  int eloc = lane >> 2;        // score-domain edge slot 0..15
  int beg = row_ptr[n];
  int deg = row_ptr[n + 1] - beg;
  int total = deg + 1;         // + implicit self-loop
  float ad2 = alpD[n * 4 + hd2];
  float lsum = 0.f;
  float a0 = 0.f, a1 = 0.f, a2 = 0.f, a3 = 0.f;
  const unsigned short* hbase = hlin + (size_t)lane * 4;

  int full = total & ~15;
  for (int base = 0; base < full; base += 16){
    int e = base + eloc;                    // always < total
    int s = (e < deg) ? csr_src[beg + e] : n;
    float xv = alpS[s * 4 + hd2] + ad2;
    float sc = (xv >= 0.f) ? xv : 0.2f * xv;
    float p = __expf(sc);
    lsum += p;
    uint2 v[16];
    #pragma unroll
    for (int j2 = 0; j2 < 16; ++j2){
      int sj = __shfl(s, j2 << 2);
      v[j2] = *(const uint2*)(hbase + (size_t)sj * 256);
    }
    #pragma unroll
    for (int j2 = 0; j2 < 16; ++j2){
      float pj = __shfl(p, (j2 << 2) | hd);
      a0 += pj * __uint_as_float(v[j2].x << 16);
      a1 += pj * __uint_as_float(v[j2].x & 0xFFFF0000u);
      a2 += pj * __uint_as_float(v[j2].y << 16);
      a3 += pj * __uint_as_float(v[j2].y & 0xFFFF0000u);
    }
  }
  int rem = total - full;                   // 0..15
  if (rem){
    int e = full + eloc;
    int s = n;
    float p = 0.f;
    if (eloc < rem){
      if (e < deg) s = csr_src[beg + e];
      float xv = alpS[s * 4 + hd2] + ad2;
      float sc = (xv >= 0.f) ? xv : 0.2f * xv;
      p = __expf(sc);
    }
    lsum += p;
    uint2 v[16];
    #pragma unroll
    for (int g = 0; g < 4; ++g){
      if (g * 4 < rem){                     // wave-uniform branch
        #pragma unroll
        for (int j2 = g * 4; j2 < g * 4 + 4; ++j2){
          int sj = __shfl(s, j2 << 2);
          v[j2] = *(const uint2*)(hbase + (size_t)sj * 256);
        }
      }
    }
    #pragma unroll
    for (int g = 0; g < 4; ++g){
      if (g * 4 < rem){
        #pragma unroll
        for (int j2 = g * 4; j2 < g * 4 + 4; ++j2){
          float pj = __shfl(p, (j2 << 2) | hd);
          a0 += pj * __uint_as_float(v[j2].x << 16);
          a1 += pj * __uint_as_float(v[j2].x & 0xFFFF0000u);
          a2 += pj * __uint_as_float(v[j2].y << 16);
          a3 += pj * __uint_as_float(v[j2].y & 0xFFFF0000u);
        }
      }
    }
  }
  lsum += __shfl_xor(lsum, 4);
  lsum += __shfl_xor(lsum, 8);
  lsum += __shfl_xor(lsum, 16);
  lsum += __shfl_xor(lsum, 32);
  float lh = __shfl(lsum, hd);
  float inv = 1.0f / lh;
  float4 bv = *(const float4*)(bias + lane * 4);
  ushort4 o;
  o.x = f2bf(a0 * inv + bv.x);
  o.y = f2bf(a1 * inv + bv.y);
  o.z = f2bf(a2 * inv + bv.z);
  o.w = f2bf(a3 * inv + bv.w);
  *(ushort4*)(outb + (size_t)n * 256 + lane * 4) = o;
}

// ---- BatchNorm stats (bf16 input) -------------------------------------------
__global__ __launch_bounds__(256) void k_bn_stats(const unsigned short* __restrict__ in,
                                                  float* __restrict__ sums,
                                                  float* __restrict__ sqs, int N){
  int t = threadIdx.x;
  int nb = gridDim.x;
  int rows = (N + nb - 1) / nb;
  int r0 = blockIdx.x * rows, r1 = min(r0 + rows, N);
  float s = 0.f, q = 0.f;
  for (int r = r0; r < r1; ++r){
    float v = bf2f(in[(size_t)r * 256 + t]);
    s += v; q += v * v;
  }
  atomicAdd(&sums[t], s);
  atomicAdd(&sqs[t], q);
}

// ---- BN apply + ELU -> bf16, fused layer-2 alphas (wave-per-node) -----------
__global__ __launch_bounds__(256) void k_bn_elu_alphas(
    const unsigned short* __restrict__ in, const float* __restrict__ sums,
    const float* __restrict__ sqs, const float* __restrict__ gamma,
    const float* __restrict__ beta, const float* __restrict__ Wa2,
    unsigned short* __restrict__ outb,
    float* __restrict__ alpS, float* __restrict__ alpD, int N, float invN){
  int lane = threadIdx.x & 63;
  int wave = blockIdx.x * 4 + (threadIdx.x >> 6);
  int nwaves = gridDim.x * 4;
  int c0 = lane * 4;
  float scl[4], sh[4];
  #pragma unroll
  for (int i = 0; i < 4; ++i){
    int c = c0 + i;
    float mean = sums[c] * invN;
    float var = sqs[c] * invN - mean * mean;
    float inv = rsqrtf(var + 1e-5f);
    scl[i] = gamma[c] * inv;
    sh[i] = beta[c] - mean * scl[i];
  }
  float wa[4][8];
  #pragma unroll
  for (int i = 0; i < 4; ++i){
    const float4* wr = (const float4*)(Wa2 + (size_t)(c0 + i) * 8);
    float4 lo = wr[0], hi = wr[1];
    wa[i][0] = lo.x; wa[i][1] = lo.y; wa[i][2] = lo.z; wa[i][3] = lo.w;
    wa[i][4] = hi.x; wa[i][5] = hi.y; wa[i][6] = hi.z; wa[i][7] = hi.w;
  }
  for (int n = wave; n < N; n += nwaves){
    ushort4 hv = *(const ushort4*)(in + (size_t)n * 256 + c0);
    float y[4];
    y[0] = scl[0] * bf2f(hv.x) + sh[0];
    y[1] = scl[1] * bf2f(hv.y) + sh[1];
    y[2] = scl[2] * bf2f(hv.z) + sh[2];
    y[3] = scl[3] * bf2f(hv.w) + sh[3];
    #pragma unroll
    for (int i = 0; i < 4; ++i) y[i] = (y[i] > 0.f) ? y[i] : (__expf(y[i]) - 1.f);
    ushort4 o; o.x = f2bf(y[0]); o.y = f2bf(y[1]); o.z = f2bf(y[2]); o.w = f2bf(y[3]);
    *(ushort4*)(outb + (size_t)n * 256 + c0) = o;
    float part[8];
    #pragma unroll
    for (int j = 0; j < 8; ++j)
      part[j] = y[0] * wa[0][j] + y[1] * wa[1][j] + y[2] * wa[2][j] + y[3] * wa[3][j];
    #pragma unroll
    for (int j = 0; j < 8; ++j){
      #pragma unroll
      for (int off = 32; off; off >>= 1) part[j] += __shfl_xor(part[j], off);
    }
    if (lane == 0){
      *(float4*)(alpS + n * 4) = make_float4(part[0], part[1], part[2], part[3]);
      *(float4*)(alpD + n * 4) = make_float4(part[4], part[5], part[6], part[7]);
    }
  }
}

// ---- BN apply + ELU + mean-pool partials (bf16 in, layer 2) -----------------
__global__ __launch_bounds__(256) void k_bn_elu_pool(
    const unsigned short* __restrict__ in, const float* __restrict__ sums,
    const float* __restrict__ sqs, const float* __restrict__ gamma,
    const float* __restrict__ beta, const int* __restrict__ batch,
    float* __restrict__ pooled, int N, float invN){
  int t = threadIdx.x;
  float mean = sums[t] * invN;
  float var = sqs[t] * invN - mean * mean;
  float inv = rsqrtf(var + 1e-5f);
  float g = gamma[t], be = beta[t];
  int nb = gridDim.x;
  int rows = (N + nb - 1) / nb;
  int r0 = blockIdx.x * rows, r1 = min(r0 + rows, N);
  float acc = 0.f; int cur = -1;
  for (int r = r0; r < r1; ++r){
    float y = g * (bf2f(in[(size_t)r * 256 + t]) - mean) * inv + be;
    y = (y > 0.f) ? y : (__expf(y) - 1.f);
    int b = batch[r];
    if (b != cur){
      if (cur >= 0) atomicAdd(&pooled[cur * 256 + t], acc);
      acc = 0.f; cur = b;
    }
    acc += y;
  }
  if (cur >= 0) atomicAdd(&pooled[cur * 256 + t], acc);
}

// ---- final FC ---------------------------------------------------------------
__global__ __launch_bounds__(128) void k_final(const float* __restrict__ pooled,
                                               const float* __restrict__ invcnt,
                                               const float* __restrict__ W_fc,
                                               const float* __restrict__ b_fc,
                                               float* __restrict__ out){
  __shared__ float pm[256];
  int b = blockIdx.x;
  int t = threadIdx.x;            // 128
  float ic = invcnt[b];
  pm[t] = pooled[b * 256 + t] * ic;
  pm[t + 128] = pooled[b * 256 + t + 128] * ic;
  __syncthreads();
  float acc = b_fc[t];
  #pragma unroll 4
  for (int c = 0; c < 256; ++c) acc += pm[c] * W_fc[c * 128 + t];
  out[b * 128 + t] = acc;
}

extern "C" void kernel_launch(void* const* d_in, const int* in_sizes, int n_in,
                              void* d_out, int out_size, void* d_ws, size_t ws_size,
                              hipStream_t stream){
  const float* x      = (const float*)d_in[0];
  const int*   eidx   = (const int*)  d_in[1];
  const int*   batch  = (const int*)  d_in[2];
  const float* W_pos  = (const float*)d_in[3];
  const float* b_pos  = (const float*)d_in[4];
  const float* W1     = (const float*)d_in[5];
  const float* a_src1 = (const float*)d_in[6];
  const float* a_dst1 = (const float*)d_in[7];
  const float* b1     = (const float*)d_in[8];
  const float* gamma1 = (const float*)d_in[9];
  const float* beta1  = (const float*)d_in[10];
  const float* W2     = (const float*)d_in[11];
  const float* a_src2 = (const float*)d_in[12];
  const float* a_dst2 = (const float*)d_in[13];
  const float* b2     = (const float*)d_in[14];
  const float* gamma2 = (const float*)d_in[15];
  const float* beta2  = (const float*)d_in[16];
  const float* W_fc   = (const float*)d_in[17];
  const float* b_fc   = (const float*)d_in[18];
  float* out = (float*)d_out;

  const int N = in_sizes[0] / 128;
  const int E = in_sizes[1] / 2;
  const int* esrc = eidx;
  const int* edst = eidx + E;

  char* w = (char*)d_ws;
  size_t off = 0;
  auto alloc = [&](size_t bytes) -> void* {
    void* p = w + off;
    off = (off + bytes + 255) & ~(size_t)255;
    return p;
  };
  unsigned short* h0   = (unsigned short*)alloc((size_t)N * 256 * 2);
  unsigned short* X2b  = h0;      // reused: disjoint lifetimes (h0 dead after GEMM1)
  unsigned short* X1b  = (unsigned short*)alloc((size_t)N * 256 * 2);  // GEMM out
  unsigned short* A1b  = (unsigned short*)alloc((size_t)N * 256 * 2);  // aggregate out
  float* alpS    = (float*)alloc((size_t)N * 4 * 4);
  float* alpD    = (float*)alloc((size_t)N * 4 * 4);
  int*   starts  = (int*)  alloc(65 * 4);
  int*   gsize   = (int*)  alloc(64 * 4);
  float* invden  = (float*)alloc(64 * 4);
  float* invcnt  = (float*)alloc(64 * 4);
  int*   indeg   = (int*)  alloc((size_t)N * 4);
  int*   row_ptr = (int*)  alloc((size_t)(N + 1) * 4);
  int*   cursor  = (int*)  alloc((size_t)(N + 1) * 4);
  int*   csr_src = (int*)  alloc((size_t)E * 4);
  int*   bsums   = (int*)  alloc(1024 * 4);
  int*   boffs   = (int*)  alloc(1024 * 4);
  float* bnstats = (float*)alloc(4 * 256 * 4);   // S1 | Q1 | S2 | Q2
  float* pooled  = (float*)alloc(64 * 256 * 4);
  unsigned short* W1t = (unsigned short*)alloc(256 * ENH_PAD * 2);
  unsigned short* W2t = (unsigned short*)alloc(256 * 256 * 2);
  float* Wa1 = (float*)alloc(144 * 8 * 4);
  float* Wa2 = (float*)alloc(256 * 8 * 4);
  float* bnS1 = bnstats, *bnQ1 = bnstats + 256, *bnS2 = bnstats + 512, *bnQ2 = bnstats + 768;

  hipMemsetAsync(indeg, 0, (size_t)N * 4, stream);

  const int NB = (N + 255) / 256;
  int nb4 = (N + 3) / 4;

  // front-end: starts + indeg + zero stats/pooled, then scan + scatter
  k_front<<<(E + 255) / 256, 256, 0, stream>>>(batch, starts, edst, indeg,
                                               bnstats, pooled, N, E);
  k_scan1<<<NB, 256, 0, stream>>>(indeg, bsums, N);
  k_scan2_meta<<<1, 1024, 0, stream>>>(bsums, boffs, row_ptr, starts,
                                       gsize, invden, invcnt, NB, N);
  k_scan3<<<NB, 256, 0, stream>>>(indeg, boffs, row_ptr, cursor, N);
  k_scatter<<<(E + 255) / 256, 256, 0, stream>>>(esrc, edst, cursor, csr_src, E);

  k_wa<<<100, 256, 0, stream>>>(W1, a_src1, a_dst1, W2, a_src2, a_dst2, Wa1, Wa2);
  k_build_h0<<<nb4, 256, 0, stream>>>(x, batch, starts, gsize, invden, W_pos, b_pos,
                                      Wa1, h0, alpS, alpD, N);
  k_pack_both<<<(256 * ENH_PAD + 256 * 256 + 255) / 256, 256, 0, stream>>>(W1, W2, W1t, W2t);

  dim3 ggrid((N + 127) / 128, 2);

  // layer 1
  k_mfma_gemm<<<ggrid, 256, 0, stream>>>(h0, W1t, X1b, N, ENH_PAD);
  k_aggregate<<<nb4, 256, 0, stream>>>(X1b, alpS, alpD, row_ptr, csr_src, b1, A1b, N);
  k_bn_stats<<<512, 256, 0, stream>>>(A1b, bnS1, bnQ1, N);
  k_bn_elu_alphas<<<256, 256, 0, stream>>>(A1b, bnS1, bnQ1, gamma1, beta1, Wa2,
                                           X2b, alpS, alpD, N, 1.0f / (float)N);

  // layer 2
  k_mfma_gemm<<<ggrid, 256, 0, stream>>>(X2b, W2t, X1b, N, 256);
  k_aggregate<<<nb4, 256, 0, stream>>>(X1b, alpS, alpD, row_ptr, csr_src, b2, A1b, N);
  k_bn_stats<<<512, 256, 0, stream>>>(A1b, bnS2, bnQ2, N);
  k_bn_elu_pool<<<512, 256, 0, stream>>>(A1b, bnS2, bnQ2, gamma2, beta2, batch,
                                         pooled, N, 1.0f / (float)N);

  // fc
  k_final<<<64, 128, 0, stream>>>(pooled, invcnt, W_fc, b_fc, out);
}

// Round 9
// 515.442 us; speedup vs baseline: 1.0970x; 1.0970x over previous
//
#include <hip/hip_runtime.h>
#include <math.h>

#define ENH_PAD 160   // 144 padded to multiple of 32 for MFMA K-loop
#define POSD 16

typedef __attribute__((ext_vector_type(8))) __bf16 bf16x8;
typedef __attribute__((ext_vector_type(4))) float f32x4;

__device__ __forceinline__ unsigned short f2bf(float f){
  unsigned int u = __float_as_uint(f);
  u += 0x7FFF + ((u >> 16) & 1);          // round-to-nearest-even
  return (unsigned short)(u >> 16);
}
__device__ __forceinline__ float bf2f(unsigned short u){
  return __uint_as_float(((unsigned int)u) << 16);
}

// ---- fused front: starts + in-degree + zero bnstats/pooled ------------------
__global__ void k_front(const int* __restrict__ batch, int* __restrict__ starts,
                        const int* __restrict__ dst, int* __restrict__ indeg,
                        float* __restrict__ bnstats, float* __restrict__ pooled,
                        int N, int E){
  int i = blockIdx.x * blockDim.x + threadIdx.x;
  if (i < 1024) bnstats[i] = 0.f;
  if (i < 64 * 256) pooled[i] = 0.f;
  if (i < N){
    int bi = batch[i];
    int bp = (i == 0) ? -1 : batch[i - 1];
    for (int b = bp + 1; b <= bi; ++b) starts[b] = i;
    if (i == N - 1){
      for (int b = bi + 1; b <= 64; ++b) starts[b] = N;
    }
  }
  if (i < E) atomicAdd(&indeg[dst[i]], 1);
}

// ---- h0 (bf16, K padded to 160): 4 nodes per block --------------------------
__global__ __launch_bounds__(256) void k_build_h0(
    const float* __restrict__ x, const int* __restrict__ batch,
    const int* __restrict__ starts, const int* __restrict__ gsize,
    const float* __restrict__ invden,
    const float* __restrict__ W_pos, const float* __restrict__ b_pos,
    unsigned short* __restrict__ h0, int N){
  int n = blockIdx.x * 4 + (threadIdx.x >> 6);
  if (n >= N) return;
  int t = threadIdx.x & 63;
  unsigned short* hrow = h0 + (size_t)n * ENH_PAD;
  if (t < 32){
    const float4* xs = (const float4*)(x + (size_t)n * 128);
    float4 v = xs[t];
    ushort4 o; o.x = f2bf(v.x); o.y = f2bf(v.y); o.z = f2bf(v.z); o.w = f2bf(v.w);
    ((ushort4*)hrow)[t] = o;
  } else if (t < 48){
    int k = t - 32;
    int b = batch[n];
    int i = n - starts[b];
    int g = gsize[b];
    int row = i / g;
    int col = i - row * g;
    float idn = invden[b];
    float pe = (float)row * idn * W_pos[k] + (float)col * idn * W_pos[POSD + k] + b_pos[k];
    hrow[128 + k] = f2bf(pe);
  } else {
    hrow[144 + (t - 48)] = 0;     // zero pad cols 144..159
  }
}

// ---- pack both weights: W [K x 256] fp32 -> Wt [256 x Kp] bf16 --------------
__global__ void k_pack_both(const float* __restrict__ W1, const float* __restrict__ W2,
                            unsigned short* __restrict__ W1t, unsigned short* __restrict__ W2t){
  int idx = blockIdx.x * 256 + threadIdx.x;
  const int n1 = 256 * ENH_PAD;
  if (idx < n1){
    int n = idx / ENH_PAD, k = idx - n * ENH_PAD;
    W1t[idx] = f2bf((k < 144) ? W1[(size_t)k * 256 + n] : 0.f);
  } else {
    int j = idx - n1;
    if (j < 256 * 256){
      int n = j >> 8, k = j & 255;
      W2t[j] = f2bf(W2[(size_t)k * 256 + n]);
    }
  }
}

// ---- bf16 MFMA GEMM + fused attention logits --------------------------------
// C[M x 256](bf16) = A[M x Kp] * Bt[256 x Kp]^T. Each wave's 64 columns form
// exactly one head -> alpS/alpD[row][head] computed from fp32 acc and stored
// by the unique owning wave (plain stores, no atomics).
#define LDST 40   // LDS row stride in bf16 (2-way bank aliasing, free)
__global__ __launch_bounds__(256) void k_mfma_gemm(
    const unsigned short* __restrict__ A, const unsigned short* __restrict__ Bt,
    unsigned short* __restrict__ C,
    const float* __restrict__ a_src, const float* __restrict__ a_dst,
    float* __restrict__ alpS, float* __restrict__ alpD, int M, int Kp){
  __shared__ unsigned short As[128 * LDST];
  __shared__ unsigned short Bs[128 * LDST];
  int t = threadIdx.x;
  int lane = t & 63, wave = t >> 6;
  int wm = (wave >> 1) * 64, wn = (wave & 1) * 64;
  int quad = lane >> 4, l16 = lane & 15;
  int row0 = blockIdx.x * 128;
  int n0 = blockIdx.y * 128;

  f32x4 acc[4][4] = {};

  int eA0 = t, eA1 = t + 256;
  for (int kk = 0; kk < Kp; kk += 32){
    #pragma unroll
    for (int rep = 0; rep < 2; ++rep){
      int e = rep ? eA1 : eA0;
      int r = e >> 2, s = e & 3;
      int grow = row0 + r;
      uint4 va = make_uint4(0, 0, 0, 0);
      if (grow < M) va = *(const uint4*)(A + (size_t)grow * Kp + kk + s * 8);
      *(uint4*)&As[r * LDST + s * 8] = va;
      uint4 vb = *(const uint4*)(Bt + (size_t)(n0 + r) * Kp + kk + s * 8);
      *(uint4*)&Bs[r * LDST + s * 8] = vb;
    }
    __syncthreads();
    bf16x8 af[4], bfr[4];
    #pragma unroll
    for (int i = 0; i < 4; ++i)
      af[i] = *(const bf16x8*)&As[(wm + i * 16 + l16) * LDST + quad * 8];
    #pragma unroll
    for (int j = 0; j < 4; ++j)
      bfr[j] = *(const bf16x8*)&Bs[(wn + j * 16 + l16) * LDST + quad * 8];
    #pragma unroll
    for (int i = 0; i < 4; ++i)
      #pragma unroll
      for (int j = 0; j < 4; ++j)
        acc[i][j] = __builtin_amdgcn_mfma_f32_16x16x32_bf16(af[i], bfr[j], acc[i][j], 0, 0, 0);
    __syncthreads();
  }
  // C store: C/D layout col=lane&15, row=quad*4+reg
  #pragma unroll
  for (int i = 0; i < 4; ++i){
    int rbase = row0 + wm + i * 16 + quad * 4;
    #pragma unroll
    for (int j = 0; j < 4; ++j){
      int col = n0 + wn + j * 16 + l16;
      #pragma unroll
      for (int r = 0; r < 4; ++r){
        int row = rbase + r;
        if (row < M) C[(size_t)row * 256 + col] = f2bf(acc[i][j][r]);
      }
    }
  }
  // fused alphas: this wave's columns n0+wn..+63 == head hda
  int hda = (n0 + wn) >> 6;
  float asw[4], adw[4];
  #pragma unroll
  for (int j = 0; j < 4; ++j){
    int c = n0 + wn + j * 16 + l16;
    asw[j] = a_src[c];
    adw[j] = a_dst[c];
  }
  #pragma unroll
  for (int i = 0; i < 4; ++i){
    #pragma unroll
    for (int r = 0; r < 4; ++r){
      int row = row0 + wm + i * 16 + quad * 4 + r;
      float ps = acc[i][0][r] * asw[0] + acc[i][1][r] * asw[1]
               + acc[i][2][r] * asw[2] + acc[i][3][r] * asw[3];
      float pd = acc[i][0][r] * adw[0] + acc[i][1][r] * adw[1]
               + acc[i][2][r] * adw[2] + acc[i][3][r] * adw[3];
      ps += __shfl_xor(ps, 1); ps += __shfl_xor(ps, 2);
      ps += __shfl_xor(ps, 4); ps += __shfl_xor(ps, 8);
      pd += __shfl_xor(pd, 1); pd += __shfl_xor(pd, 2);
      pd += __shfl_xor(pd, 4); pd += __shfl_xor(pd, 8);
      if (l16 == 0 && row < M){
        alpS[row * 4 + hda] = ps;
        alpD[row * 4 + hda] = pd;
      }
    }
  }
}

// ---- parallel scan of indeg -> row_ptr / cursor -----------------------------
__device__ __forceinline__ int block_excl_scan_256(int val, int* lds){
  int t = threadIdx.x;
  int lane = t & 63, w = t >> 6;
  int incl = val;
  #pragma unroll
  for (int off = 1; off < 64; off <<= 1){
    int v = __shfl_up(incl, off);
    if (lane >= off) incl += v;
  }
  if (lane == 63) lds[w] = incl;
  __syncthreads();
  int wofs = 0;
  #pragma unroll
  for (int i = 0; i < 4; ++i) if (i < w) wofs += lds[i];
  return wofs + incl - val;
}

__global__ __launch_bounds__(256) void k_scan1(const int* __restrict__ indeg,
                                               int* __restrict__ bsums, int N){
  int i = blockIdx.x * 256 + threadIdx.x;
  int v = (i < N) ? indeg[i] : 0;
  int s = v;
  #pragma unroll
  for (int off = 32; off; off >>= 1) s += __shfl_xor(s, off);
  __shared__ int wt[4];
  if ((threadIdx.x & 63) == 0) wt[threadIdx.x >> 6] = s;
  __syncthreads();
  if (threadIdx.x == 0) bsums[blockIdx.x] = wt[0] + wt[1] + wt[2] + wt[3];
}

__global__ __launch_bounds__(1024) void k_scan2_meta(const int* __restrict__ bsums,
                                                     int* __restrict__ boffs,
                                                     int* __restrict__ row_ptr,
                                                     const int* __restrict__ starts,
                                                     int* __restrict__ gsize,
                                                     float* __restrict__ invden,
                                                     float* __restrict__ invcnt,
                                                     int NB, int N){
  int t = threadIdx.x;
  if (t < 64){
    int c = starts[t + 1] - starts[t];
    int g = (int)ceilf(sqrtf((float)c));
    gsize[t] = g;
    int dd = g - 1; if (dd < 1) dd = 1;
    invden[t] = 1.0f / (float)dd;
    invcnt[t] = (c > 0) ? 1.0f / (float)c : 0.0f;
  }
  int v = (t < NB) ? bsums[t] : 0;
  int lane = t & 63, w = t >> 6;
  int incl = v;
  #pragma unroll
  for (int off = 1; off < 64; off <<= 1){
    int x = __shfl_up(incl, off);
    if (lane >= off) incl += x;
  }
  __shared__ int wt[16];
  if (lane == 63) wt[w] = incl;
  __syncthreads();
  int wofs = 0;
  for (int i = 0; i < w; ++i) wofs += wt[i];
  if (t < NB) boffs[t] = wofs + incl - v;
  if (t == 1023){
    int tot = 0;
    for (int i = 0; i < 16; ++i) tot += wt[i];
    row_ptr[N] = tot;
  }
}

__global__ __launch_bounds__(256) void k_scan3(const int* __restrict__ indeg,
                                               const int* __restrict__ boffs,
                                               int* __restrict__ row_ptr,
                                               int* __restrict__ cursor, int N){
  __shared__ int lds[4];
  int i = blockIdx.x * 256 + threadIdx.x;
  int v = (i < N) ? indeg[i] : 0;
  int ex = block_excl_scan_256(v, lds) + boffs[blockIdx.x];
  if (i < N){
    row_ptr[i] = ex;
    cursor[i] = ex;
  }
}

__global__ void k_scatter(const int* __restrict__ src, const int* __restrict__ dst,
                          int* cursor, int* __restrict__ csr_src, int E){
  int e = blockIdx.x * blockDim.x + threadIdx.x;
  if (e < E){
    int slot = atomicAdd(&cursor[dst[e]], 1);
    csr_src[slot] = src[e];
  }
}

// ---- GAT aggregation: one wave/node, 4 heads, batched gathers.
//      Full-16 chunks (no per-edge validity tests) + 4-granular tail. --------
__global__ __launch_bounds__(256) void k_aggregate(const unsigned short* __restrict__ hlin,
                                                   const float* __restrict__ alpS,
                                                   const float* __restrict__ alpD,
                                                   const int* __restrict__ row_ptr,
                                                   const int* __restrict__ csr_src,
                                                   const float* __restrict__ bias,
                                                   unsigned short* __restrict__ outb, int N){
  int n = blockIdx.x * 4 + (threadIdx.x >> 6);
  if (n >= N) return;
  int lane = threadIdx.x & 63;
  int hd = lane >> 4;          // channel-domain head
  int hd2 = lane & 3;          // score-domain head
  int eloc = lane >> 2;        // score-domain edge slot 0..15
  int beg = row_ptr[n];
  int deg = row_ptr[n + 1] - beg;
  int total = deg + 1;         // + implicit self-loop
  float ad2 = alpD[n * 4 + hd2];
  float lsum = 0.f;
  float a0 = 0.f, a1 = 0.f, a2 = 0.f, a3 = 0.f;
  const unsigned short* hbase = hlin + (size_t)lane * 4;

  int full = total & ~15;
  for (int base = 0; base < full; base += 16){
    int e = base + eloc;                    // always < total
    int s = (e < deg) ? csr_src[beg + e] : n;
    float xv = alpS[s * 4 + hd2] + ad2;
    float sc = (xv >= 0.f) ? xv : 0.2f * xv;
    float p = __expf(sc);
    lsum += p;
    uint2 v[16];
    #pragma unroll
    for (int j2 = 0; j2 < 16; ++j2){
      int sj = __shfl(s, j2 << 2);
      v[j2] = *(const uint2*)(hbase + (size_t)sj * 256);
    }
    #pragma unroll
    for (int j2 = 0; j2 < 16; ++j2){
      float pj = __shfl(p, (j2 << 2) | hd);
      a0 += pj * __uint_as_float(v[j2].x << 16);
      a1 += pj * __uint_as_float(v[j2].x & 0xFFFF0000u);
      a2 += pj * __uint_as_float(v[j2].y << 16);
      a3 += pj * __uint_as_float(v[j2].y & 0xFFFF0000u);
    }
  }
  int rem = total - full;                   // 0..15
  if (rem){
    int e = full + eloc;
    int s = n;
    float p = 0.f;
    if (eloc < rem){
      if (e < deg) s = csr_src[beg + e];
      float xv = alpS[s * 4 + hd2] + ad2;
      float sc = (xv >= 0.f) ? xv : 0.2f * xv;
      p = __expf(sc);
    }
    lsum += p;
    uint2 v[16];
    #pragma unroll
    for (int g = 0; g < 4; ++g){
      if (g * 4 < rem){                     // wave-uniform branch
        #pragma unroll
        for (int j2 = g * 4; j2 < g * 4 + 4; ++j2){
          int sj = __shfl(s, j2 << 2);
          v[j2] = *(const uint2*)(hbase + (size_t)sj * 256);
        }
      }
    }
    #pragma unroll
    for (int g = 0; g < 4; ++g){
      if (g * 4 < rem){
        #pragma unroll
        for (int j2 = g * 4; j2 < g * 4 + 4; ++j2){
          float pj = __shfl(p, (j2 << 2) | hd);
          a0 += pj * __uint_as_float(v[j2].x << 16);
          a1 += pj * __uint_as_float(v[j2].x & 0xFFFF0000u);
          a2 += pj * __uint_as_float(v[j2].y << 16);
          a3 += pj * __uint_as_float(v[j2].y & 0xFFFF0000u);
        }
      }
    }
  }
  lsum += __shfl_xor(lsum, 4);
  lsum += __shfl_xor(lsum, 8);
  lsum += __shfl_xor(lsum, 16);
  lsum += __shfl_xor(lsum, 32);
  float lh = __shfl(lsum, hd);
  float inv = 1.0f / lh;
  float4 bv = *(const float4*)(bias + lane * 4);
  ushort4 o;
  o.x = f2bf(a0 * inv + bv.x);
  o.y = f2bf(a1 * inv + bv.y);
  o.z = f2bf(a2 * inv + bv.z);
  o.w = f2bf(a3 * inv + bv.w);
  *(ushort4*)(outb + (size_t)n * 256 + lane * 4) = o;
}

// ---- BatchNorm stats (bf16 input) -------------------------------------------
__global__ __launch_bounds__(256) void k_bn_stats(const unsigned short* __restrict__ in,
                                                  float* __restrict__ sums,
                                                  float* __restrict__ sqs, int N){
  int t = threadIdx.x;
  int nb = gridDim.x;
  int rows = (N + nb - 1) / nb;
  int r0 = blockIdx.x * rows, r1 = min(r0 + rows, N);
  float s = 0.f, q = 0.f;
  for (int r = r0; r < r1; ++r){
    float v = bf2f(in[(size_t)r * 256 + t]);
    s += v; q += v * v;
  }
  atomicAdd(&sums[t], s);
  atomicAdd(&sqs[t], q);
}

// ---- BN apply + ELU (bf16 in -> bf16 out, layer 1) --------------------------
__global__ void k_bn_elu_bf16(const unsigned short* __restrict__ in,
                              const float* __restrict__ sums,
                              const float* __restrict__ sqs, const float* __restrict__ gamma,
                              const float* __restrict__ beta,
                              unsigned short* __restrict__ outb, int N, float invN){
  int idx = blockIdx.x * blockDim.x + threadIdx.x;
  int total = N * 256;
  for (; idx < total; idx += gridDim.x * blockDim.x){
    int c = idx & 255;
    float mean = sums[c] * invN;
    float var = sqs[c] * invN - mean * mean;
    float inv = rsqrtf(var + 1e-5f);
    float y = gamma[c] * (bf2f(in[idx]) - mean) * inv + beta[c];
    y = (y > 0.f) ? y : (__expf(y) - 1.f);
    outb[idx] = f2bf(y);
  }
}

// ---- BN apply + ELU + mean-pool partials (bf16 in, layer 2) -----------------
__global__ __launch_bounds__(256) void k_bn_elu_pool(
    const unsigned short* __restrict__ in, const float* __restrict__ sums,
    const float* __restrict__ sqs, const float* __restrict__ gamma,
    const float* __restrict__ beta, const int* __restrict__ batch,
    float* __restrict__ pooled, int N, float invN){
  int t = threadIdx.x;
  float mean = sums[t] * invN;
  float var = sqs[t] * invN - mean * mean;
  float inv = rsqrtf(var + 1e-5f);
  float g = gamma[t], be = beta[t];
  int nb = gridDim.x;
  int rows = (N + nb - 1) / nb;
  int r0 = blockIdx.x * rows, r1 = min(r0 + rows, N);
  float acc = 0.f; int cur = -1;
  for (int r = r0; r < r1; ++r){
    float y = g * (bf2f(in[(size_t)r * 256 + t]) - mean) * inv + be;
    y = (y > 0.f) ? y : (__expf(y) - 1.f);
    int b = batch[r];
    if (b != cur){
      if (cur >= 0) atomicAdd(&pooled[cur * 256 + t], acc);
      acc = 0.f; cur = b;
    }
    acc += y;
  }
  if (cur >= 0) atomicAdd(&pooled[cur * 256 + t], acc);
}

// ---- final FC ---------------------------------------------------------------
__global__ __launch_bounds__(128) void k_final(const float* __restrict__ pooled,
                                               const float* __restrict__ invcnt,
                                               const float* __restrict__ W_fc,
                                               const float* __restrict__ b_fc,
                                               float* __restrict__ out){
  __shared__ float pm[256];
  int b = blockIdx.x;
  int t = threadIdx.x;            // 128
  float ic = invcnt[b];
  pm[t] = pooled[b * 256 + t] * ic;
  pm[t + 128] = pooled[b * 256 + t + 128] * ic;
  __syncthreads();
  float acc = b_fc[t];
  #pragma unroll 4
  for (int c = 0; c < 256; ++c) acc += pm[c] * W_fc[c * 128 + t];
  out[b * 128 + t] = acc;
}

extern "C" void kernel_launch(void* const* d_in, const int* in_sizes, int n_in,
                              void* d_out, int out_size, void* d_ws, size_t ws_size,
                              hipStream_t stream){
  const float* x      = (const float*)d_in[0];
  const int*   eidx   = (const int*)  d_in[1];
  const int*   batch  = (const int*)  d_in[2];
  const float* W_pos  = (const float*)d_in[3];
  const float* b_pos  = (const float*)d_in[4];
  const float* W1     = (const float*)d_in[5];
  const float* a_src1 = (const float*)d_in[6];
  const float* a_dst1 = (const float*)d_in[7];
  const float* b1     = (const float*)d_in[8];
  const float* gamma1 = (const float*)d_in[9];
  const float* beta1  = (const float*)d_in[10];
  const float* W2     = (const float*)d_in[11];
  const float* a_src2 = (const float*)d_in[12];
  const float* a_dst2 = (const float*)d_in[13];
  const float* b2     = (const float*)d_in[14];
  const float* gamma2 = (const float*)d_in[15];
  const float* beta2  = (const float*)d_in[16];
  const float* W_fc   = (const float*)d_in[17];
  const float* b_fc   = (const float*)d_in[18];
  float* out = (float*)d_out;

  const int N = in_sizes[0] / 128;
  const int E = in_sizes[1] / 2;
  const int* esrc = eidx;
  const int* edst = eidx + E;

  char* w = (char*)d_ws;
  size_t off = 0;
  auto alloc = [&](size_t bytes) -> void* {
    void* p = w + off;
    off = (off + bytes + 255) & ~(size_t)255;
    return p;
  };
  unsigned short* h0   = (unsigned short*)alloc((size_t)N * 256 * 2);
  unsigned short* X2b  = h0;      // reused: disjoint lifetimes (h0 dead after GEMM1)
  unsigned short* X1b  = (unsigned short*)alloc((size_t)N * 256 * 2);  // GEMM out
  unsigned short* A1b  = (unsigned short*)alloc((size_t)N * 256 * 2);  // aggregate out
  float* alpS    = (float*)alloc((size_t)N * 4 * 4);
  float* alpD    = (float*)alloc((size_t)N * 4 * 4);
  int*   starts  = (int*)  alloc(65 * 4);
  int*   gsize   = (int*)  alloc(64 * 4);
  float* invden  = (float*)alloc(64 * 4);
  float* invcnt  = (float*)alloc(64 * 4);
  int*   indeg   = (int*)  alloc((size_t)N * 4);
  int*   row_ptr = (int*)  alloc((size_t)(N + 1) * 4);
  int*   cursor  = (int*)  alloc((size_t)(N + 1) * 4);
  int*   csr_src = (int*)  alloc((size_t)E * 4);
  int*   bsums   = (int*)  alloc(1024 * 4);
  int*   boffs   = (int*)  alloc(1024 * 4);
  float* bnstats = (float*)alloc(4 * 256 * 4);   // S1 | Q1 | S2 | Q2
  float* pooled  = (float*)alloc(64 * 256 * 4);
  unsigned short* W1t = (unsigned short*)alloc(256 * ENH_PAD * 2);
  unsigned short* W2t = (unsigned short*)alloc(256 * 256 * 2);
  float* bnS1 = bnstats, *bnQ1 = bnstats + 256, *bnS2 = bnstats + 512, *bnQ2 = bnstats + 768;

  hipMemsetAsync(indeg, 0, (size_t)N * 4, stream);

  const int NB = (N + 255) / 256;
  int nb4 = (N + 3) / 4;

  // front-end: starts + indeg + zero stats/pooled, then scan + scatter
  k_front<<<(E + 255) / 256, 256, 0, stream>>>(batch, starts, edst, indeg,
                                               bnstats, pooled, N, E);
  k_scan1<<<NB, 256, 0, stream>>>(indeg, bsums, N);
  k_scan2_meta<<<1, 1024, 0, stream>>>(bsums, boffs, row_ptr, starts,
                                       gsize, invden, invcnt, NB, N);
  k_scan3<<<NB, 256, 0, stream>>>(indeg, boffs, row_ptr, cursor, N);
  k_scatter<<<(E + 255) / 256, 256, 0, stream>>>(esrc, edst, cursor, csr_src, E);

  k_build_h0<<<nb4, 256, 0, stream>>>(x, batch, starts, gsize, invden, W_pos, b_pos, h0, N);
  k_pack_both<<<(256 * ENH_PAD + 256 * 256 + 255) / 256, 256, 0, stream>>>(W1, W2, W1t, W2t);

  dim3 ggrid((N + 127) / 128, 2);

  // layer 1
  k_mfma_gemm<<<ggrid, 256, 0, stream>>>(h0, W1t, X1b, a_src1, a_dst1, alpS, alpD, N, ENH_PAD);
  k_aggregate<<<nb4, 256, 0, stream>>>(X1b, alpS, alpD, row_ptr, csr_src, b1, A1b, N);
  k_bn_stats<<<512, 256, 0, stream>>>(A1b, bnS1, bnQ1, N);
  k_bn_elu_bf16<<<4096, 256, 0, stream>>>(A1b, bnS1, bnQ1, gamma1, beta1, X2b, N, 1.0f / (float)N);

  // layer 2
  k_mfma_gemm<<<ggrid, 256, 0, stream>>>(X2b, W2t, X1b, a_src2, a_dst2, alpS, alpD, N, 256);
  k_aggregate<<<nb4, 256, 0, stream>>>(X1b, alpS, alpD, row_ptr, csr_src, b2, A1b, N);
  k_bn_stats<<<512, 256, 0, stream>>>(A1b, bnS2, bnQ2, N);
  k_bn_elu_pool<<<512, 256, 0, stream>>>(A1b, bnS2, bnQ2, gamma2, beta2, batch,
                                         pooled, N, 1.0f / (float)N);

  // fc
  k_final<<<64, 128, 0, stream>>>(pooled, invcnt, W_fc, b_fc, out);
}